// Round 8
// baseline (402.000 us; speedup 1.0000x reference)
//
#include <hip/hip_runtime.h>

#define B_DIM 8
#define S_LEN 4096
#define D_DIM 512
#define H_DIM 512

#define DECAY_F 0.90483743f   // exp(-0.1)
#define ALPHA_F 0.01f
#define EPS_F   1e-6f

// ---------------- GEMM: h[m][n] = sum_k x[m][k] * W[n][k] + bias[n] ----------------
// FROZEN from R7 (214us): 128x128 tile, KT=16, single-buffer LDS, register prefetch,
// 8x8 wave grid tr=lane>>3 / tc=lane&7, cols {c0,c0+32}, NO min-waves bound
// (a (256,3) bound squeezes VGPRs -> store fragmentation -> 7x WRITE amplification).
// Per-element k-accumulation order identical since R2 -> bit-identical h.
#define KT 16
__global__ __launch_bounds__(256) void gemm_kernel(const float* __restrict__ x,
                                                   const float* __restrict__ W,
                                                   const float* __restrict__ bias,
                                                   float* __restrict__ out) {
    __shared__ float As[KT][132];
    __shared__ float Bs[KT][132];

    const int tid = threadIdx.x;
    const int waveId = tid >> 6;
    const int waveR = waveId & 1;        // row half of 128
    const int waveC = waveId >> 1;       // col half of 128
    const int lane = tid & 63;
    const int tr = lane >> 3;            // 0..7 (row index within wave)
    const int tc = lane & 7;             // 0..7 (col index, lane-fast)
    const int rbase = waveR * 64 + tr * 8;
    const int c0 = waveC * 64 + tc * 4;  // first col group
    const int c1 = c0 + 32;              // second col group
    const int bm = blockIdx.y * 128;
    const int bn = blockIdx.x * 128;

    const int lrow = tid >> 2;          // 0..63
    const int lk4  = (tid & 3) * 4;     // 0,4,8,12

    const float* xa = &x[(size_t)(bm + lrow) * D_DIM + lk4];
    const float* xb = &x[(size_t)(bm + lrow + 64) * D_DIM + lk4];
    const float* wa = &W[(size_t)(bn + lrow) * D_DIM + lk4];
    const float* wb = &W[(size_t)(bn + lrow + 64) * D_DIM + lk4];

    float acc[8][8];
#pragma unroll
    for (int i = 0; i < 8; ++i)
#pragma unroll
        for (int j = 0; j < 8; ++j) acc[i][j] = 0.f;

    // prologue: stage tile kk=0 into registers
    float4 a0 = *reinterpret_cast<const float4*>(xa);
    float4 a1 = *reinterpret_cast<const float4*>(xb);
    float4 b0 = *reinterpret_cast<const float4*>(wa);
    float4 b1 = *reinterpret_cast<const float4*>(wb);

    for (int kk = 0; kk < D_DIM; kk += KT) {
        __syncthreads();
        As[lk4 + 0][lrow]      = a0.x;
        As[lk4 + 1][lrow]      = a0.y;
        As[lk4 + 2][lrow]      = a0.z;
        As[lk4 + 3][lrow]      = a0.w;
        As[lk4 + 0][lrow + 64] = a1.x;
        As[lk4 + 1][lrow + 64] = a1.y;
        As[lk4 + 2][lrow + 64] = a1.z;
        As[lk4 + 3][lrow + 64] = a1.w;
        Bs[lk4 + 0][lrow]      = b0.x;
        Bs[lk4 + 1][lrow]      = b0.y;
        Bs[lk4 + 2][lrow]      = b0.z;
        Bs[lk4 + 3][lrow]      = b0.w;
        Bs[lk4 + 0][lrow + 64] = b1.x;
        Bs[lk4 + 1][lrow + 64] = b1.y;
        Bs[lk4 + 2][lrow + 64] = b1.z;
        Bs[lk4 + 3][lrow + 64] = b1.w;
        __syncthreads();

        // issue next tile's loads; latency hides under the FMA loop below
        if (kk + KT < D_DIM) {
            a0 = *reinterpret_cast<const float4*>(xa + kk + KT);
            a1 = *reinterpret_cast<const float4*>(xb + kk + KT);
            b0 = *reinterpret_cast<const float4*>(wa + kk + KT);
            b1 = *reinterpret_cast<const float4*>(wb + kk + KT);
        }

#pragma unroll
        for (int k = 0; k < KT; ++k) {
            const float4 av0 = *reinterpret_cast<const float4*>(&As[k][rbase]);
            const float4 av1 = *reinterpret_cast<const float4*>(&As[k][rbase + 4]);
            const float4 bv0 = *reinterpret_cast<const float4*>(&Bs[k][c0]);
            const float4 bv1 = *reinterpret_cast<const float4*>(&Bs[k][c1]);
            const float am[8]  = {av0.x, av0.y, av0.z, av0.w, av1.x, av1.y, av1.z, av1.w};
            const float bn_[8] = {bv0.x, bv0.y, bv0.z, bv0.w, bv1.x, bv1.y, bv1.z, bv1.w};
#pragma unroll
            for (int i = 0; i < 8; ++i)
#pragma unroll
                for (int j = 0; j < 8; ++j) acc[i][j] += am[i] * bn_[j];
        }
    }

    const float4 bias0 = *reinterpret_cast<const float4*>(&bias[bn + c0]);
    const float4 bias1 = *reinterpret_cast<const float4*>(&bias[bn + c1]);
    const float bb[8] = {bias0.x, bias0.y, bias0.z, bias0.w, bias1.x, bias1.y, bias1.z, bias1.w};

#pragma unroll
    for (int i = 0; i < 8; ++i) {
        const size_t row = (size_t)(bm + rbase + i);
        float4 o0, o1;
        o0.x = acc[i][0] + bb[0]; o0.y = acc[i][1] + bb[1];
        o0.z = acc[i][2] + bb[2]; o0.w = acc[i][3] + bb[3];
        o1.x = acc[i][4] + bb[4]; o1.y = acc[i][5] + bb[5];
        o1.z = acc[i][6] + bb[6]; o1.w = acc[i][7] + bb[7];
        *reinterpret_cast<float4*>(&out[row * H_DIM + bn + c0]) = o0;
        *reinterpret_cast<float4*>(&out[row * H_DIM + bn + c1]) = o1;
    }
}

// ---------------- Scan ----------------
// LDS staging via global_load_lds, double-buffered [2][32][64], counted vmcnt,
// 8-deep register read-ring, per-step sched_barrier (R5: removing it cost ~50us).
// R8 chain shortening (11 -> 8 dependent ops per step):
//  - med3 clamps tied in-place ("+v", no copies); 0 as inline constant.
//  - 1-step Markstein quotient (q0,e1,nv) with r0 = correctly-rounded reciprocal
//    via TWO Newton refinements computed off the critical path (prev step's theta).
//    Markstein: RN(r0) + one fma-refinement => correctly-rounded quotient = np's div.

__device__ __forceinline__ void stage_chunk(const float* __restrict__ gio, float* dstbase,
                                            int c, int lane) {
    const float* src = gio + (size_t)(c * 32 + (lane >> 4)) * H_DIM + ((lane & 15) << 2);
#pragma unroll
    for (int i = 0; i < 8; ++i) {
        __builtin_amdgcn_global_load_lds(
            (const __attribute__((address_space(1))) void*)(src + (size_t)i * 4 * H_DIM),
            (__attribute__((address_space(3))) void*)(dstbase + i * 256),
            16, 0, 0);
    }
}

__global__ __launch_bounds__(64, 1) void scan_kernel(float* __restrict__ io,
                                                     float* __restrict__ vout,
                                                     float* __restrict__ thout) {
    __shared__ float sbuf[2][32][64];

    const int lane = threadIdx.x;
    const int bi = blockIdx.x;        // 0..63
    const int b = bi >> 3;            // 0..7
    const int h0 = (bi & 7) << 6;     // 0,64,...,448

    float* gio = io + (size_t)b * S_LEN * H_DIM + h0;

    float v = 0.f;
    float theta = 1.f;
    float tden = theta + EPS_F;
    // correctly-rounded reciprocal seed (2 Newton steps)
    float rs = __builtin_amdgcn_rcpf(tden);
    float es = fmaf(-tden, rs, 1.0f);
    float r1 = fmaf(es, rs, rs);
    float es2 = fmaf(-tden, r1, 1.0f);
    float r0 = fmaf(es2, r1, r1);
    float cl = 32.f * theta;
    const float kSixteen = 16.0f;

    stage_chunk(gio, &sbuf[0][0][0], 0, lane);
    asm volatile("s_waitcnt vmcnt(0)" ::: "memory");

    const int NCHUNK = S_LEN / 32;    // 128
    for (int c = 0; c < NCHUNK; ++c) {
        if (c + 1 < NCHUNK) {
            stage_chunk(gio, &sbuf[(c + 1) & 1][0][0], c + 1, lane);
            // outstanding: stage(c)=8, stores(c-1)=32, stage(c+1)=8 -> retire oldest 8.
            asm volatile("s_waitcnt vmcnt(40)" ::: "memory");
        } else {
            asm volatile("s_waitcnt vmcnt(32)" ::: "memory");
        }
        __builtin_amdgcn_sched_barrier(0);

        const float* sb = &sbuf[c & 1][0][lane];
        float* gout = gio + (size_t)c * 32 * H_DIM + lane;

        float rb[8];
#pragma unroll
        for (int i = 0; i < 8; ++i) rb[i] = sb[i * 64];

#pragma unroll
        for (int u = 0; u < 32; ++u) {
            const float it = rb[u & 7];
            if (u + 8 < 32) rb[u & 7] = sb[(u + 8) * 64];   // issue ds_read ~8 steps early

            v = v * DECAY_F + it;
            // v = clamp(v, -cl, cl), in-place, bit-exact (cl >= 32, v never NaN)
            asm("v_med3_f32 %0, %0, -%1, %1" : "+v"(v) : "v"(cl));

            // nv = RN(v / tden): r0 is the RN reciprocal (2 Newtons, off-path below),
            // one Markstein fma-refinement gives the correctly rounded quotient.
            const float q0 = v * r0;
            const float e1 = fmaf(-tden, q0, v);
            const float nv = fmaf(e1, r0, q0);

            float spike = floorf(nv);
            // spike = clamp(spike, 0, 16), in-place, bit-exact
            asm("v_med3_f32 %0, %0, 0, %1" : "+v"(spike) : "v"(kSixteen));

            v = v - spike * theta;
            theta = theta + ALPHA_F * spike - ALPHA_F * (theta - 1.0f);

            // off-critical-path: next step's denominator, RN reciprocal, clamp bound
            tden = theta + EPS_F;
            const float rr = __builtin_amdgcn_rcpf(tden);
            const float ee = fmaf(-tden, rr, 1.0f);
            const float ra = fmaf(ee, rr, rr);
            const float ee2 = fmaf(-tden, ra, 1.0f);
            r0 = fmaf(ee2, ra, ra);
            cl = 32.f * theta;

            gout[(size_t)u * H_DIM] = spike;
            __builtin_amdgcn_sched_barrier(0);
        }
    }

    const int chain = b * H_DIM + h0 + lane;
    vout[chain]  = v;
    thout[chain] = theta;
}

extern "C" void kernel_launch(void* const* d_in, const int* in_sizes, int n_in,
                              void* d_out, int out_size, void* d_ws, size_t ws_size,
                              hipStream_t stream) {
    const float* x    = (const float*)d_in[0];
    const float* W    = (const float*)d_in[1];
    const float* bias = (const float*)d_in[2];

    float* out   = (float*)d_out;
    float* vout  = out + (size_t)B_DIM * S_LEN * H_DIM;
    float* thout = vout + B_DIM * H_DIM;

    dim3 grid(H_DIM / 128, (B_DIM * S_LEN) / 128);
    gemm_kernel<<<grid, 256, 0, stream>>>(x, W, bias, out);

    scan_kernel<<<64, 64, 0, stream>>>(out, vout, thout);
}

// Round 9
// 389.477 us; speedup vs baseline: 1.0322x; 1.0322x over previous
//
#include <hip/hip_runtime.h>

#define B_DIM 8
#define S_LEN 4096
#define D_DIM 512
#define H_DIM 512

#define DECAY_F 0.90483743f   // exp(-0.1)
#define ALPHA_F 0.01f
#define EPS_F   1e-6f

// ---------------- GEMM: h[m][n] = sum_k x[m][k] * W[n][k] + bias[n] ----------------
// FROZEN from R7 (214us): 128x128 tile, KT=16, single-buffer LDS, register prefetch,
// 8x8 wave grid tr=lane>>3 / tc=lane&7, cols {c0,c0+32}, NO min-waves bound
// (a (256,3) bound squeezes VGPRs -> store fragmentation -> 7x WRITE amplification).
// Per-element k-accumulation order identical since R2 -> bit-identical h.
#define KT 16
__global__ __launch_bounds__(256) void gemm_kernel(const float* __restrict__ x,
                                                   const float* __restrict__ W,
                                                   const float* __restrict__ bias,
                                                   float* __restrict__ out) {
    __shared__ float As[KT][132];
    __shared__ float Bs[KT][132];

    const int tid = threadIdx.x;
    const int waveId = tid >> 6;
    const int waveR = waveId & 1;        // row half of 128
    const int waveC = waveId >> 1;       // col half of 128
    const int lane = tid & 63;
    const int tr = lane >> 3;            // 0..7 (row index within wave)
    const int tc = lane & 7;             // 0..7 (col index, lane-fast)
    const int rbase = waveR * 64 + tr * 8;
    const int c0 = waveC * 64 + tc * 4;  // first col group
    const int c1 = c0 + 32;              // second col group
    const int bm = blockIdx.y * 128;
    const int bn = blockIdx.x * 128;

    const int lrow = tid >> 2;          // 0..63
    const int lk4  = (tid & 3) * 4;     // 0,4,8,12

    const float* xa = &x[(size_t)(bm + lrow) * D_DIM + lk4];
    const float* xb = &x[(size_t)(bm + lrow + 64) * D_DIM + lk4];
    const float* wa = &W[(size_t)(bn + lrow) * D_DIM + lk4];
    const float* wb = &W[(size_t)(bn + lrow + 64) * D_DIM + lk4];

    float acc[8][8];
#pragma unroll
    for (int i = 0; i < 8; ++i)
#pragma unroll
        for (int j = 0; j < 8; ++j) acc[i][j] = 0.f;

    // prologue: stage tile kk=0 into registers
    float4 a0 = *reinterpret_cast<const float4*>(xa);
    float4 a1 = *reinterpret_cast<const float4*>(xb);
    float4 b0 = *reinterpret_cast<const float4*>(wa);
    float4 b1 = *reinterpret_cast<const float4*>(wb);

    for (int kk = 0; kk < D_DIM; kk += KT) {
        __syncthreads();
        As[lk4 + 0][lrow]      = a0.x;
        As[lk4 + 1][lrow]      = a0.y;
        As[lk4 + 2][lrow]      = a0.z;
        As[lk4 + 3][lrow]      = a0.w;
        As[lk4 + 0][lrow + 64] = a1.x;
        As[lk4 + 1][lrow + 64] = a1.y;
        As[lk4 + 2][lrow + 64] = a1.z;
        As[lk4 + 3][lrow + 64] = a1.w;
        Bs[lk4 + 0][lrow]      = b0.x;
        Bs[lk4 + 1][lrow]      = b0.y;
        Bs[lk4 + 2][lrow]      = b0.z;
        Bs[lk4 + 3][lrow]      = b0.w;
        Bs[lk4 + 0][lrow + 64] = b1.x;
        Bs[lk4 + 1][lrow + 64] = b1.y;
        Bs[lk4 + 2][lrow + 64] = b1.z;
        Bs[lk4 + 3][lrow + 64] = b1.w;
        __syncthreads();

        // issue next tile's loads; latency hides under the FMA loop below
        if (kk + KT < D_DIM) {
            a0 = *reinterpret_cast<const float4*>(xa + kk + KT);
            a1 = *reinterpret_cast<const float4*>(xb + kk + KT);
            b0 = *reinterpret_cast<const float4*>(wa + kk + KT);
            b1 = *reinterpret_cast<const float4*>(wb + kk + KT);
        }

#pragma unroll
        for (int k = 0; k < KT; ++k) {
            const float4 av0 = *reinterpret_cast<const float4*>(&As[k][rbase]);
            const float4 av1 = *reinterpret_cast<const float4*>(&As[k][rbase + 4]);
            const float4 bv0 = *reinterpret_cast<const float4*>(&Bs[k][c0]);
            const float4 bv1 = *reinterpret_cast<const float4*>(&Bs[k][c1]);
            const float am[8]  = {av0.x, av0.y, av0.z, av0.w, av1.x, av1.y, av1.z, av1.w};
            const float bn_[8] = {bv0.x, bv0.y, bv0.z, bv0.w, bv1.x, bv1.y, bv1.z, bv1.w};
#pragma unroll
            for (int i = 0; i < 8; ++i)
#pragma unroll
                for (int j = 0; j < 8; ++j) acc[i][j] += am[i] * bn_[j];
        }
    }

    const float4 bias0 = *reinterpret_cast<const float4*>(&bias[bn + c0]);
    const float4 bias1 = *reinterpret_cast<const float4*>(&bias[bn + c1]);
    const float bb[8] = {bias0.x, bias0.y, bias0.z, bias0.w, bias1.x, bias1.y, bias1.z, bias1.w};

#pragma unroll
    for (int i = 0; i < 8; ++i) {
        const size_t row = (size_t)(bm + rbase + i);
        float4 o0, o1;
        o0.x = acc[i][0] + bb[0]; o0.y = acc[i][1] + bb[1];
        o0.z = acc[i][2] + bb[2]; o0.w = acc[i][3] + bb[3];
        o1.x = acc[i][4] + bb[4]; o1.y = acc[i][5] + bb[5];
        o1.z = acc[i][6] + bb[6]; o1.w = acc[i][7] + bb[7];
        *reinterpret_cast<float4*>(&out[row * H_DIM + bn + c0]) = o0;
        *reinterpret_cast<float4*>(&out[row * H_DIM + bn + c1]) = o1;
    }
}

// ---------------- Scan ----------------
// R9 restructure: phase-split chunks.
//   phase A: stage chunk c+1 via global_load_lds; counted vmcnt retires stage(c).
//   phase B: bulk-read ALL 32 staged values for chunk c from LDS into registers
//            (one lgkm wait per chunk instead of per step).
//   phase C: 32 steps of pure-register recurrence + global stores; NO LDS ops,
//            no per-step fences.
// Per-step arithmetic statements identical to R8 (absmax 0.0 verified).

__device__ __forceinline__ void stage_chunk(const float* __restrict__ gio, float* dstbase,
                                            int c, int lane) {
    const float* src = gio + (size_t)(c * 32 + (lane >> 4)) * H_DIM + ((lane & 15) << 2);
#pragma unroll
    for (int i = 0; i < 8; ++i) {
        __builtin_amdgcn_global_load_lds(
            (const __attribute__((address_space(1))) void*)(src + (size_t)i * 4 * H_DIM),
            (__attribute__((address_space(3))) void*)(dstbase + i * 256),
            16, 0, 0);
    }
}

__global__ __launch_bounds__(64, 1) void scan_kernel(float* __restrict__ io,
                                                     float* __restrict__ vout,
                                                     float* __restrict__ thout) {
    __shared__ float sbuf[2][32][64];

    const int lane = threadIdx.x;
    const int bi = blockIdx.x;        // 0..63
    const int b = bi >> 3;            // 0..7
    const int h0 = (bi & 7) << 6;     // 0,64,...,448

    float* gio = io + (size_t)b * S_LEN * H_DIM + h0;

    float v = 0.f;
    float theta = 1.f;
    float tden = theta + EPS_F;
    // correctly-rounded reciprocal seed (2 Newton steps)
    float rs = __builtin_amdgcn_rcpf(tden);
    float es = fmaf(-tden, rs, 1.0f);
    float r1 = fmaf(es, rs, rs);
    float es2 = fmaf(-tden, r1, 1.0f);
    float r0 = fmaf(es2, r1, r1);
    float cl = 32.f * theta;
    const float kSixteen = 16.0f;

    stage_chunk(gio, &sbuf[0][0][0], 0, lane);
    asm volatile("s_waitcnt vmcnt(0)" ::: "memory");

    const int NCHUNK = S_LEN / 32;    // 128
    for (int c = 0; c < NCHUNK; ++c) {
        // ---- phase A: prefetch next chunk, retire stage(c) ----
        if (c + 1 < NCHUNK) {
            stage_chunk(gio, &sbuf[(c + 1) & 1][0][0], c + 1, lane);
            // outstanding: stage(c)=8, stores(c-1)=32, stage(c+1)=8 -> retire oldest 8.
            asm volatile("s_waitcnt vmcnt(40)" ::: "memory");
        } else {
            asm volatile("s_waitcnt vmcnt(32)" ::: "memory");
        }
        __builtin_amdgcn_sched_barrier(0);

        // ---- phase B: bulk LDS -> registers (single lgkm wait for the chunk) ----
        const float* sb = &sbuf[c & 1][0][lane];
        float rr[32];
#pragma unroll
        for (int i = 0; i < 32; ++i) rr[i] = sb[i * 64];
        __builtin_amdgcn_sched_barrier(0);

        // ---- phase C: pure-register recurrence ----
        float* gout = gio + (size_t)c * 32 * H_DIM + lane;

#pragma unroll
        for (int u = 0; u < 32; ++u) {
            float vv = v * DECAY_F + rr[u];
            // v = clamp(v, -cl, cl), in-place, bit-exact (cl >= 32, v never NaN)
            asm("v_med3_f32 %0, %0, -%1, %1" : "+v"(vv) : "v"(cl));
            v = vv;

            // nv = RN(v / tden): r0 is the RN reciprocal (2 Newtons, off-path below),
            // one Markstein fma-refinement gives the correctly rounded quotient.
            const float q0 = v * r0;
            const float e1 = fmaf(-tden, q0, v);
            const float nv = fmaf(e1, r0, q0);

            float spike = floorf(nv);
            // spike = clamp(spike, 0, 16), in-place, bit-exact
            asm("v_med3_f32 %0, %0, 0, %1" : "+v"(spike) : "v"(kSixteen));

            v = v - spike * theta;
            theta = theta + ALPHA_F * spike - ALPHA_F * (theta - 1.0f);

            // off-critical-path: next step's denominator, RN reciprocal, clamp bound
            tden = theta + EPS_F;
            const float rrcp = __builtin_amdgcn_rcpf(tden);
            const float ee = fmaf(-tden, rrcp, 1.0f);
            const float ra = fmaf(ee, rrcp, rrcp);
            const float ee2 = fmaf(-tden, ra, 1.0f);
            r0 = fmaf(ee2, ra, ra);
            cl = 32.f * theta;

            gout[(size_t)u * H_DIM] = spike;
        }
        __builtin_amdgcn_sched_barrier(0);
    }

    const int chain = b * H_DIM + h0 + lane;
    vout[chain]  = v;
    thout[chain] = theta;
}

extern "C" void kernel_launch(void* const* d_in, const int* in_sizes, int n_in,
                              void* d_out, int out_size, void* d_ws, size_t ws_size,
                              hipStream_t stream) {
    const float* x    = (const float*)d_in[0];
    const float* W    = (const float*)d_in[1];
    const float* bias = (const float*)d_in[2];

    float* out   = (float*)d_out;
    float* vout  = out + (size_t)B_DIM * S_LEN * H_DIM;
    float* thout = vout + B_DIM * H_DIM;

    dim3 grid(H_DIM / 128, (B_DIM * S_LEN) / 128);
    gemm_kernel<<<grid, 256, 0, stream>>>(x, W, bias, out);

    scan_kernel<<<64, 64, 0, stream>>>(out, vout, thout);
}

// Round 10
// 349.295 us; speedup vs baseline: 1.1509x; 1.1150x over previous
//
#include <hip/hip_runtime.h>

#define B_DIM 8
#define S_LEN 4096
#define D_DIM 512
#define H_DIM 512

#define DECAY_F 0.90483743f   // exp(-0.1)
#define ALPHA_F 0.01f
#define EPS_F   1e-6f

#define KT 16
#define NCHUNK (S_LEN / 32)   // 128
#define NSCAN_BLOCKS 16

// ================= shared device helpers =================

__device__ __forceinline__ void stage_chunk(const float* __restrict__ gio, float* dstbase,
                                            int c, int lane) {
    const float* src = gio + (size_t)(c * 32 + (lane >> 4)) * H_DIM + ((lane & 15) << 2);
#pragma unroll
    for (int i = 0; i < 8; ++i) {
        __builtin_amdgcn_global_load_lds(
            (const __attribute__((address_space(1))) void*)(src + (size_t)i * 4 * H_DIM),
            (__attribute__((address_space(3))) void*)(dstbase + i * 256),
            16, 0, 0);
    }
}

// GEMM tile body: computes 128x128 tile at (bm, bn). Accumulation order identical
// to R2-R9 -> bit-identical h. As/Bs are [KT][132] float arrays in LDS.
__device__ __forceinline__ void gemm_tile(const float* __restrict__ x,
                                          const float* __restrict__ W,
                                          const float* __restrict__ bias,
                                          float* __restrict__ out,
                                          float (*As)[132], float (*Bs)[132],
                                          int bm, int bn) {
    const int tid = threadIdx.x;
    const int waveId = tid >> 6;
    const int waveR = waveId & 1;
    const int waveC = waveId >> 1;
    const int lane = tid & 63;
    const int tr = lane >> 3;
    const int tc = lane & 7;
    const int rbase = waveR * 64 + tr * 8;
    const int c0 = waveC * 64 + tc * 4;
    const int c1 = c0 + 32;

    const int lrow = tid >> 2;
    const int lk4  = (tid & 3) * 4;

    const float* xa = &x[(size_t)(bm + lrow) * D_DIM + lk4];
    const float* xb = &x[(size_t)(bm + lrow + 64) * D_DIM + lk4];
    const float* wa = &W[(size_t)(bn + lrow) * D_DIM + lk4];
    const float* wb = &W[(size_t)(bn + lrow + 64) * D_DIM + lk4];

    float acc[8][8];
#pragma unroll
    for (int i = 0; i < 8; ++i)
#pragma unroll
        for (int j = 0; j < 8; ++j) acc[i][j] = 0.f;

    float4 a0 = *reinterpret_cast<const float4*>(xa);
    float4 a1 = *reinterpret_cast<const float4*>(xb);
    float4 b0 = *reinterpret_cast<const float4*>(wa);
    float4 b1 = *reinterpret_cast<const float4*>(wb);

    for (int kk = 0; kk < D_DIM; kk += KT) {
        __syncthreads();
        As[lk4 + 0][lrow]      = a0.x;
        As[lk4 + 1][lrow]      = a0.y;
        As[lk4 + 2][lrow]      = a0.z;
        As[lk4 + 3][lrow]      = a0.w;
        As[lk4 + 0][lrow + 64] = a1.x;
        As[lk4 + 1][lrow + 64] = a1.y;
        As[lk4 + 2][lrow + 64] = a1.z;
        As[lk4 + 3][lrow + 64] = a1.w;
        Bs[lk4 + 0][lrow]      = b0.x;
        Bs[lk4 + 1][lrow]      = b0.y;
        Bs[lk4 + 2][lrow]      = b0.z;
        Bs[lk4 + 3][lrow]      = b0.w;
        Bs[lk4 + 0][lrow + 64] = b1.x;
        Bs[lk4 + 1][lrow + 64] = b1.y;
        Bs[lk4 + 2][lrow + 64] = b1.z;
        Bs[lk4 + 3][lrow + 64] = b1.w;
        __syncthreads();

        if (kk + KT < D_DIM) {
            a0 = *reinterpret_cast<const float4*>(xa + kk + KT);
            a1 = *reinterpret_cast<const float4*>(xb + kk + KT);
            b0 = *reinterpret_cast<const float4*>(wa + kk + KT);
            b1 = *reinterpret_cast<const float4*>(wb + kk + KT);
        }

#pragma unroll
        for (int k = 0; k < KT; ++k) {
            const float4 av0 = *reinterpret_cast<const float4*>(&As[k][rbase]);
            const float4 av1 = *reinterpret_cast<const float4*>(&As[k][rbase + 4]);
            const float4 bv0 = *reinterpret_cast<const float4*>(&Bs[k][c0]);
            const float4 bv1 = *reinterpret_cast<const float4*>(&Bs[k][c1]);
            const float am[8]  = {av0.x, av0.y, av0.z, av0.w, av1.x, av1.y, av1.z, av1.w};
            const float bn_[8] = {bv0.x, bv0.y, bv0.z, bv0.w, bv1.x, bv1.y, bv1.z, bv1.w};
#pragma unroll
            for (int i = 0; i < 8; ++i)
#pragma unroll
                for (int j = 0; j < 8; ++j) acc[i][j] += am[i] * bn_[j];
        }
    }

    const float4 bias0 = *reinterpret_cast<const float4*>(&bias[bn + c0]);
    const float4 bias1 = *reinterpret_cast<const float4*>(&bias[bn + c1]);
    const float bb[8] = {bias0.x, bias0.y, bias0.z, bias0.w, bias1.x, bias1.y, bias1.z, bias1.w};

#pragma unroll
    for (int i = 0; i < 8; ++i) {
        const size_t row = (size_t)(bm + rbase + i);
        float4 o0, o1;
        o0.x = acc[i][0] + bb[0]; o0.y = acc[i][1] + bb[1];
        o0.z = acc[i][2] + bb[2]; o0.w = acc[i][3] + bb[3];
        o1.x = acc[i][4] + bb[4]; o1.y = acc[i][5] + bb[5];
        o1.z = acc[i][6] + bb[6]; o1.w = acc[i][7] + bb[7];
        *reinterpret_cast<float4*>(&out[row * H_DIM + bn + c0]) = o0;
        *reinterpret_cast<float4*>(&out[row * H_DIM + bn + c1]) = o1;
    }
}

// Scan for one 64-chain group (one wave). Per-step math identical to R9 (absmax 0.0).
// If flagrow != nullptr, acquire-polls flagrow[st] == 4 before staging s-tile st.
__device__ __forceinline__ void scan_wave(float* __restrict__ gio, float* sbuf,
                                          const int* flagrow, int lane,
                                          float* __restrict__ vout,
                                          float* __restrict__ thout, int chain) {
    float v = 0.f;
    float theta = 1.f;
    float tden = theta + EPS_F;
    float rs = __builtin_amdgcn_rcpf(tden);
    float es = fmaf(-tden, rs, 1.0f);
    float r1 = fmaf(es, rs, rs);
    float es2 = fmaf(-tden, r1, 1.0f);
    float r0 = fmaf(es2, r1, r1);
    float cl = 32.f * theta;
    const float kSixteen = 16.0f;

    if (flagrow) {
        while (__hip_atomic_load(&flagrow[0], __ATOMIC_ACQUIRE, __HIP_MEMORY_SCOPE_AGENT) < 4)
            __builtin_amdgcn_s_sleep(1);
    }
    stage_chunk(gio, sbuf, 0, lane);
    asm volatile("s_waitcnt vmcnt(0)" ::: "memory");

    for (int c = 0; c < NCHUNK; ++c) {
        if (c + 1 < NCHUNK) {
            if (((c + 1) & 3) == 0 && flagrow) {
                const int stn = (c + 1) >> 2;
                while (__hip_atomic_load(&flagrow[stn], __ATOMIC_ACQUIRE,
                                         __HIP_MEMORY_SCOPE_AGENT) < 4)
                    __builtin_amdgcn_s_sleep(1);
                // poll consumption drained vmcnt -> stage(c) complete; make it explicit
                asm volatile("s_waitcnt vmcnt(0)" ::: "memory");
                stage_chunk(gio, sbuf + ((c + 1) & 1) * 2048, c + 1, lane);
            } else {
                stage_chunk(gio, sbuf + ((c + 1) & 1) * 2048, c + 1, lane);
                // outstanding: stage(c)=8, stores(c-1)=32, stage(c+1)=8 -> retire oldest 8
                asm volatile("s_waitcnt vmcnt(40)" ::: "memory");
            }
        } else {
            asm volatile("s_waitcnt vmcnt(32)" ::: "memory");
        }
        __builtin_amdgcn_sched_barrier(0);

        // bulk LDS -> registers (one lgkm wait per chunk)
        const float* sb = sbuf + (c & 1) * 2048 + lane;
        float rr[32];
#pragma unroll
        for (int i = 0; i < 32; ++i) rr[i] = sb[i * 64];
        __builtin_amdgcn_sched_barrier(0);

        float* gout = gio + (size_t)c * 32 * H_DIM + lane;

#pragma unroll
        for (int u = 0; u < 32; ++u) {
            float vv = v * DECAY_F + rr[u];
            asm("v_med3_f32 %0, %0, -%1, %1" : "+v"(vv) : "v"(cl));
            v = vv;

            const float q0 = v * r0;
            const float e1 = fmaf(-tden, q0, v);
            const float nv = fmaf(e1, r0, q0);

            float spike = floorf(nv);
            asm("v_med3_f32 %0, %0, 0, %1" : "+v"(spike) : "v"(kSixteen));

            v = v - spike * theta;
            theta = theta + ALPHA_F * spike - ALPHA_F * (theta - 1.0f);

            tden = theta + EPS_F;
            const float rrcp = __builtin_amdgcn_rcpf(tden);
            const float ee = fmaf(-tden, rrcp, 1.0f);
            const float ra = fmaf(ee, rrcp, rrcp);
            const float ee2 = fmaf(-tden, ra, 1.0f);
            r0 = fmaf(ee2, ra, ra);
            cl = 32.f * theta;

            gout[(size_t)u * H_DIM] = spike;
        }
        __builtin_amdgcn_sched_barrier(0);
    }

    vout[chain]  = v;
    thout[chain] = theta;
}

// ================= fused producer/consumer kernel =================
// blocks 0..15: scan (4 waves each, one 64-chain group per wave).
// blocks 16..1039: GEMM tiles, s-tile-major order: g = st*32 + b*4 + nt,
//   so h is produced in exactly the order the scan consumes it.
// Sync: flags[b*32+st] counters in d_ws; GEMM block: __syncthreads (drains stores)
// + one agent-scope RELEASE fetch_add; scan: agent-scope ACQUIRE poll ==4
// (release sequence through the 4 RMWs -> all 4 tiles' stores visible; acquire
// invalidates reader-XCD caches). No deadlock: 16 spinner blocks can never
// starve GEMM of CUs, and GEMM blocks never wait.
__global__ __launch_bounds__(256) void fused_kernel(const float* __restrict__ x,
                                                    const float* __restrict__ W,
                                                    const float* __restrict__ bias,
                                                    float* __restrict__ out,
                                                    float* __restrict__ vout,
                                                    float* __restrict__ thout,
                                                    int* __restrict__ flags) {
    __shared__ __align__(16) char smem_raw[65536];
    const int bid = blockIdx.x;

    if (bid >= NSCAN_BLOCKS) {
        float (*As)[132] = reinterpret_cast<float (*)[132]>(smem_raw);
        float (*Bs)[132] = reinterpret_cast<float (*)[132]>(smem_raw + sizeof(float) * KT * 132);

        const int g  = bid - NSCAN_BLOCKS;
        const int st = g >> 5;          // s-tile 0..31 (outer -> s-order completion)
        const int bb = (g >> 2) & 7;    // batch
        const int nt = g & 3;           // n-tile
        const int bm = bb * S_LEN + st * 128;
        const int bn = nt * 128;

        gemm_tile(x, W, bias, out, As, Bs, bm, bn);

        __syncthreads();   // each wave drains vmcnt before barrier -> all stores retired
        if (threadIdx.x == 0) {
            __hip_atomic_fetch_add(&flags[bb * 32 + st], 1,
                                   __ATOMIC_RELEASE, __HIP_MEMORY_SCOPE_AGENT);
        }
        return;
    }

    // scan role
    const int w    = threadIdx.x >> 6;
    const int lane = threadIdx.x & 63;
    const int gi   = bid * 4 + w;          // 0..63
    const int b    = gi >> 3;
    const int h0   = (gi & 7) << 6;

    float* sbuf = reinterpret_cast<float*>(smem_raw) + w * (2 * 32 * 64);
    const int* flagrow = flags + b * 32;
    float* gio = out + (size_t)b * S_LEN * H_DIM + h0;
    const int chain = b * H_DIM + h0 + lane;

    scan_wave(gio, sbuf, flagrow, lane, vout, thout, chain);
}

// ================= fallback serial kernels (ws_size too small) =================

__global__ __launch_bounds__(256) void gemm_kernel(const float* __restrict__ x,
                                                   const float* __restrict__ W,
                                                   const float* __restrict__ bias,
                                                   float* __restrict__ out) {
    __shared__ float As[KT][132];
    __shared__ float Bs[KT][132];
    const int bm = blockIdx.y * 128;
    const int bn = blockIdx.x * 128;
    gemm_tile(x, W, bias, out, As, Bs, bm, bn);
}

__global__ __launch_bounds__(64, 1) void scan_kernel(float* __restrict__ io,
                                                     float* __restrict__ vout,
                                                     float* __restrict__ thout) {
    __shared__ float sbuf[2][32][64];
    const int lane = threadIdx.x;
    const int bi = blockIdx.x;
    const int b = bi >> 3;
    const int h0 = (bi & 7) << 6;
    float* gio = io + (size_t)b * S_LEN * H_DIM + h0;
    const int chain = b * H_DIM + h0 + lane;
    scan_wave(gio, &sbuf[0][0][0], nullptr, lane, vout, thout, chain);
}

extern "C" void kernel_launch(void* const* d_in, const int* in_sizes, int n_in,
                              void* d_out, int out_size, void* d_ws, size_t ws_size,
                              hipStream_t stream) {
    const float* x    = (const float*)d_in[0];
    const float* W    = (const float*)d_in[1];
    const float* bias = (const float*)d_in[2];

    float* out   = (float*)d_out;
    float* vout  = out + (size_t)B_DIM * S_LEN * H_DIM;
    float* thout = vout + B_DIM * H_DIM;

    if (ws_size >= 1024) {
        int* flags = (int*)d_ws;
        hipMemsetAsync(flags, 0, 256 * sizeof(int), stream);
        fused_kernel<<<NSCAN_BLOCKS + 1024, 256, 0, stream>>>(x, W, bias, out,
                                                              vout, thout, flags);
    } else {
        dim3 grid(H_DIM / 128, (B_DIM * S_LEN) / 128);
        gemm_kernel<<<grid, 256, 0, stream>>>(x, W, bias, out);
        scan_kernel<<<64, 64, 0, stream>>>(out, vout, thout);
    }
}

// Round 11
// 334.080 us; speedup vs baseline: 1.2033x; 1.0455x over previous
//
#include <hip/hip_runtime.h>

#define B_DIM 8
#define S_LEN 4096
#define D_DIM 512
#define H_DIM 512

#define DECAY_F 0.90483743f   // exp(-0.1)
#define ALPHA_F 0.01f
#define EPS_F   1e-6f

#define KT 16
#define NCHUNK (S_LEN / 32)   // 128
#define NSCAN_BLOCKS 64

// ================= shared device helpers =================

__device__ __forceinline__ void stage_chunk(const float* __restrict__ gio, float* dstbase,
                                            int c, int lane) {
    const float* src = gio + (size_t)(c * 32 + (lane >> 4)) * H_DIM + ((lane & 15) << 2);
#pragma unroll
    for (int i = 0; i < 8; ++i) {
        __builtin_amdgcn_global_load_lds(
            (const __attribute__((address_space(1))) void*)(src + (size_t)i * 4 * H_DIM),
            (__attribute__((address_space(3))) void*)(dstbase + i * 256),
            16, 0, 0);
    }
}

// GEMM tile body: computes 128x128 tile at (bm, bn). Accumulation order identical
// to R2-R10 -> bit-identical h. As/Bs are [KT][132] float arrays in LDS.
__device__ __forceinline__ void gemm_tile(const float* __restrict__ x,
                                          const float* __restrict__ W,
                                          const float* __restrict__ bias,
                                          float* __restrict__ out,
                                          float (*As)[132], float (*Bs)[132],
                                          int bm, int bn) {
    const int tid = threadIdx.x;
    const int waveId = tid >> 6;
    const int waveR = waveId & 1;
    const int waveC = waveId >> 1;
    const int lane = tid & 63;
    const int tr = lane >> 3;
    const int tc = lane & 7;
    const int rbase = waveR * 64 + tr * 8;
    const int c0 = waveC * 64 + tc * 4;
    const int c1 = c0 + 32;

    const int lrow = tid >> 2;
    const int lk4  = (tid & 3) * 4;

    const float* xa = &x[(size_t)(bm + lrow) * D_DIM + lk4];
    const float* xb = &x[(size_t)(bm + lrow + 64) * D_DIM + lk4];
    const float* wa = &W[(size_t)(bn + lrow) * D_DIM + lk4];
    const float* wb = &W[(size_t)(bn + lrow + 64) * D_DIM + lk4];

    float acc[8][8];
#pragma unroll
    for (int i = 0; i < 8; ++i)
#pragma unroll
        for (int j = 0; j < 8; ++j) acc[i][j] = 0.f;

    float4 a0 = *reinterpret_cast<const float4*>(xa);
    float4 a1 = *reinterpret_cast<const float4*>(xb);
    float4 b0 = *reinterpret_cast<const float4*>(wa);
    float4 b1 = *reinterpret_cast<const float4*>(wb);

    for (int kk = 0; kk < D_DIM; kk += KT) {
        __syncthreads();
        As[lk4 + 0][lrow]      = a0.x;
        As[lk4 + 1][lrow]      = a0.y;
        As[lk4 + 2][lrow]      = a0.z;
        As[lk4 + 3][lrow]      = a0.w;
        As[lk4 + 0][lrow + 64] = a1.x;
        As[lk4 + 1][lrow + 64] = a1.y;
        As[lk4 + 2][lrow + 64] = a1.z;
        As[lk4 + 3][lrow + 64] = a1.w;
        Bs[lk4 + 0][lrow]      = b0.x;
        Bs[lk4 + 1][lrow]      = b0.y;
        Bs[lk4 + 2][lrow]      = b0.z;
        Bs[lk4 + 3][lrow]      = b0.w;
        Bs[lk4 + 0][lrow + 64] = b1.x;
        Bs[lk4 + 1][lrow + 64] = b1.y;
        Bs[lk4 + 2][lrow + 64] = b1.z;
        Bs[lk4 + 3][lrow + 64] = b1.w;
        __syncthreads();

        if (kk + KT < D_DIM) {
            a0 = *reinterpret_cast<const float4*>(xa + kk + KT);
            a1 = *reinterpret_cast<const float4*>(xb + kk + KT);
            b0 = *reinterpret_cast<const float4*>(wa + kk + KT);
            b1 = *reinterpret_cast<const float4*>(wb + kk + KT);
        }

#pragma unroll
        for (int k = 0; k < KT; ++k) {
            const float4 av0 = *reinterpret_cast<const float4*>(&As[k][rbase]);
            const float4 av1 = *reinterpret_cast<const float4*>(&As[k][rbase + 4]);
            const float4 bv0 = *reinterpret_cast<const float4*>(&Bs[k][c0]);
            const float4 bv1 = *reinterpret_cast<const float4*>(&Bs[k][c1]);
            const float am[8]  = {av0.x, av0.y, av0.z, av0.w, av1.x, av1.y, av1.z, av1.w};
            const float bn_[8] = {bv0.x, bv0.y, bv0.z, bv0.w, bv1.x, bv1.y, bv1.z, bv1.w};
#pragma unroll
            for (int i = 0; i < 8; ++i)
#pragma unroll
                for (int j = 0; j < 8; ++j) acc[i][j] += am[i] * bn_[j];
        }
    }

    const float4 bias0 = *reinterpret_cast<const float4*>(&bias[bn + c0]);
    const float4 bias1 = *reinterpret_cast<const float4*>(&bias[bn + c1]);
    const float bb[8] = {bias0.x, bias0.y, bias0.z, bias0.w, bias1.x, bias1.y, bias1.z, bias1.w};

#pragma unroll
    for (int i = 0; i < 8; ++i) {
        const size_t row = (size_t)(bm + rbase + i);
        float4 o0, o1;
        o0.x = acc[i][0] + bb[0]; o0.y = acc[i][1] + bb[1];
        o0.z = acc[i][2] + bb[2]; o0.w = acc[i][3] + bb[3];
        o1.x = acc[i][4] + bb[4]; o1.y = acc[i][5] + bb[5];
        o1.z = acc[i][6] + bb[6]; o1.w = acc[i][7] + bb[7];
        *reinterpret_cast<float4*>(&out[row * H_DIM + bn + c0]) = o0;
        *reinterpret_cast<float4*>(&out[row * H_DIM + bn + c1]) = o1;
    }
}

// Scan for one 64-chain group (one wave). Per-step math identical to R9/R10 (absmax 0.0).
// If flagrow != nullptr, acquire-polls flagrow[st] == 4 before staging s-tile st.
__device__ __forceinline__ void scan_wave(float* __restrict__ gio, float* sbuf,
                                          const int* flagrow, int lane,
                                          float* __restrict__ vout,
                                          float* __restrict__ thout, int chain) {
    float v = 0.f;
    float theta = 1.f;
    float tden = theta + EPS_F;
    float rs = __builtin_amdgcn_rcpf(tden);
    float es = fmaf(-tden, rs, 1.0f);
    float r1 = fmaf(es, rs, rs);
    float es2 = fmaf(-tden, r1, 1.0f);
    float r0 = fmaf(es2, r1, r1);
    float cl = 32.f * theta;
    const float kSixteen = 16.0f;

    if (flagrow) {
        while (__hip_atomic_load(&flagrow[0], __ATOMIC_ACQUIRE, __HIP_MEMORY_SCOPE_AGENT) < 4)
            __builtin_amdgcn_s_sleep(1);
    }
    stage_chunk(gio, sbuf, 0, lane);
    asm volatile("s_waitcnt vmcnt(0)" ::: "memory");

    for (int c = 0; c < NCHUNK; ++c) {
        if (c + 1 < NCHUNK) {
            if (((c + 1) & 3) == 0 && flagrow) {
                const int stn = (c + 1) >> 2;
                while (__hip_atomic_load(&flagrow[stn], __ATOMIC_ACQUIRE,
                                         __HIP_MEMORY_SCOPE_AGENT) < 4)
                    __builtin_amdgcn_s_sleep(1);
                // poll consumed time; drain then stage next s-tile's first chunk
                asm volatile("s_waitcnt vmcnt(0)" ::: "memory");
                stage_chunk(gio, sbuf + ((c + 1) & 1) * 2048, c + 1, lane);
            } else {
                stage_chunk(gio, sbuf + ((c + 1) & 1) * 2048, c + 1, lane);
                // outstanding: stage(c)=8, stores(c-1)=32, stage(c+1)=8 -> retire oldest 8
                asm volatile("s_waitcnt vmcnt(40)" ::: "memory");
            }
        } else {
            asm volatile("s_waitcnt vmcnt(32)" ::: "memory");
        }
        __builtin_amdgcn_sched_barrier(0);

        // bulk LDS -> registers (one lgkm wait per chunk)
        const float* sb = sbuf + (c & 1) * 2048 + lane;
        float rr[32];
#pragma unroll
        for (int i = 0; i < 32; ++i) rr[i] = sb[i * 64];
        __builtin_amdgcn_sched_barrier(0);

        float* gout = gio + (size_t)c * 32 * H_DIM + lane;

#pragma unroll
        for (int u = 0; u < 32; ++u) {
            float vv = v * DECAY_F + rr[u];
            asm("v_med3_f32 %0, %0, -%1, %1" : "+v"(vv) : "v"(cl));
            v = vv;

            const float q0 = v * r0;
            const float e1 = fmaf(-tden, q0, v);
            const float nv = fmaf(e1, r0, q0);

            float spike = floorf(nv);
            asm("v_med3_f32 %0, %0, 0, %1" : "+v"(spike) : "v"(kSixteen));

            v = v - spike * theta;
            theta = theta + ALPHA_F * spike - ALPHA_F * (theta - 1.0f);

            tden = theta + EPS_F;
            const float rrcp = __builtin_amdgcn_rcpf(tden);
            const float ee = fmaf(-tden, rrcp, 1.0f);
            const float ra = fmaf(ee, rrcp, rrcp);
            const float ee2 = fmaf(-tden, ra, 1.0f);
            r0 = fmaf(ee2, ra, ra);
            cl = 32.f * theta;

            gout[(size_t)u * H_DIM] = spike;
        }
        __builtin_amdgcn_sched_barrier(0);
    }

    vout[chain]  = v;
    thout[chain] = theta;
}

// ================= fused producer/consumer kernel =================
// blocks 0..63: scan, ONE active wave each (threads 64..255 exit immediately),
//   16 KB LDS double-buffer, s_setprio(1) so the latency-critical chain wins
//   SIMD arbitration against co-resident GEMM waves (they're throughput-bound;
//   scan issues ~1/7 of slots, so GEMM cost is minimal).
// blocks 64..1087: GEMM tiles, s-tile-major: g = st*32 + b*4 + nt -> h produced
//   in exactly the order the scan consumes it.
// Static LDS = max(16896 GEMM, 16384 scan) = 16896 B -> GEMM residency ~R7 level.
// Sync: flags[b*32+st]; GEMM: __syncthreads (stores drained) + RELEASE fetch_add;
// scan: ACQUIRE poll ==4. Proven absmax 0.0 in R10.
__global__ __launch_bounds__(256) void fused_kernel(const float* __restrict__ x,
                                                    const float* __restrict__ W,
                                                    const float* __restrict__ bias,
                                                    float* __restrict__ out,
                                                    float* __restrict__ vout,
                                                    float* __restrict__ thout,
                                                    int* __restrict__ flags) {
    __shared__ __align__(16) char smem_raw[16896];
    const int bid = blockIdx.x;

    if (bid >= NSCAN_BLOCKS) {
        float (*As)[132] = reinterpret_cast<float (*)[132]>(smem_raw);
        float (*Bs)[132] = reinterpret_cast<float (*)[132]>(smem_raw + sizeof(float) * KT * 132);

        const int g  = bid - NSCAN_BLOCKS;
        const int st = g >> 5;          // s-tile 0..31 (outer -> s-order completion)
        const int bb = (g >> 2) & 7;    // batch
        const int nt = g & 3;           // n-tile
        const int bm = bb * S_LEN + st * 128;
        const int bn = nt * 128;

        gemm_tile(x, W, bias, out, As, Bs, bm, bn);

        __syncthreads();   // all waves' stores retired before the release add
        if (threadIdx.x == 0) {
            __hip_atomic_fetch_add(&flags[bb * 32 + st], 1,
                                   __ATOMIC_RELEASE, __HIP_MEMORY_SCOPE_AGENT);
        }
        return;
    }

    // scan role: one wave per block
    if (threadIdx.x >= 64) return;
    __builtin_amdgcn_s_setprio(1);

    const int lane = threadIdx.x;
    const int gi   = bid;                  // 0..63
    const int b    = gi >> 3;
    const int h0   = (gi & 7) << 6;

    float* sbuf = reinterpret_cast<float*>(smem_raw);
    const int* flagrow = flags + b * 32;
    float* gio = out + (size_t)b * S_LEN * H_DIM + h0;
    const int chain = b * H_DIM + h0 + lane;

    scan_wave(gio, sbuf, flagrow, lane, vout, thout, chain);
}

// ================= fallback serial kernels (ws_size too small) =================

__global__ __launch_bounds__(256) void gemm_kernel(const float* __restrict__ x,
                                                   const float* __restrict__ W,
                                                   const float* __restrict__ bias,
                                                   float* __restrict__ out) {
    __shared__ float As[KT][132];
    __shared__ float Bs[KT][132];
    const int bm = blockIdx.y * 128;
    const int bn = blockIdx.x * 128;
    gemm_tile(x, W, bias, out, As, Bs, bm, bn);
}

__global__ __launch_bounds__(64, 1) void scan_kernel(float* __restrict__ io,
                                                     float* __restrict__ vout,
                                                     float* __restrict__ thout) {
    __shared__ float sbuf[2][32][64];
    const int lane = threadIdx.x;
    const int bi = blockIdx.x;
    const int b = bi >> 3;
    const int h0 = (bi & 7) << 6;
    float* gio = io + (size_t)b * S_LEN * H_DIM + h0;
    const int chain = b * H_DIM + h0 + lane;
    scan_wave(gio, &sbuf[0][0][0], nullptr, lane, vout, thout, chain);
}

extern "C" void kernel_launch(void* const* d_in, const int* in_sizes, int n_in,
                              void* d_out, int out_size, void* d_ws, size_t ws_size,
                              hipStream_t stream) {
    const float* x    = (const float*)d_in[0];
    const float* W    = (const float*)d_in[1];
    const float* bias = (const float*)d_in[2];

    float* out   = (float*)d_out;
    float* vout  = out + (size_t)B_DIM * S_LEN * H_DIM;
    float* thout = vout + B_DIM * H_DIM;

    if (ws_size >= 1024) {
        int* flags = (int*)d_ws;
        hipMemsetAsync(flags, 0, 256 * sizeof(int), stream);
        fused_kernel<<<NSCAN_BLOCKS + 1024, 256, 0, stream>>>(x, W, bias, out,
                                                              vout, thout, flags);
    } else {
        dim3 grid(H_DIM / 128, (B_DIM * S_LEN) / 128);
        gemm_kernel<<<grid, 256, 0, stream>>>(x, W, bias, out);
        scan_kernel<<<64, 64, 0, stream>>>(out, vout, thout);
    }
}